// Round 2
// baseline (936.070 us; speedup 1.0000x reference)
//
#include <hip/hip_runtime.h>
#include <hip/hip_bf16.h>

#define NCODES 8192
#define DIM    64
#define NROWS  65536   // 16*4096

// ---- workspace layout (float offsets) ----
#define WS_EBIAS   0         // 8192
#define WS_COUNTS  8192      // 8192
#define WS_DW      16384     // 524288
#define WS_LOSSP   540672    // 512
#define WS_NCSP    541184    // 32
#define WS_N       541216    // 1
#define WS_END     541217

// ---- output layout (float offsets, tuple order) ----
#define OUT_ZQ     0                     // 4194304
#define OUT_IDX    4194304               // 65536
#define OUT_LOSS   4259840               // 1
#define OUT_NEMB   4259841               // 524288
#define OUT_NCS    4784129               // 8192
#define OUT_NEMA   4792321               // 524288

#define BR   128
#define BC   128
#define LDZ  68     // padded LDS row stride (floats); rows tr+16i -> 2-way bank alias only

// ||e_k||^2 for each code
__global__ void vq_ebias_kernel(const float* __restrict__ emb, float* __restrict__ ebias) {
    int k = blockIdx.x * 256 + threadIdx.x;
    const float4* e4 = reinterpret_cast<const float4*>(emb + (size_t)k * DIM);
    float s = 0.f;
#pragma unroll
    for (int i = 0; i < 16; i++) {
        float4 v = e4[i];
        s = fmaf(v.x, v.x, s); s = fmaf(v.y, v.y, s);
        s = fmaf(v.z, v.z, s); s = fmaf(v.w, v.w, s);
    }
    ebias[k] = s;
}

// Main: distances + argmin + gather + z_q_st + loss partial + counts/dw scatter
__global__ __launch_bounds__(256, 2)
void vq_main_kernel(const float* __restrict__ z, const float* __restrict__ emb,
                    const float* __restrict__ ebias, float* __restrict__ out,
                    float* __restrict__ counts, float* __restrict__ dw,
                    float* __restrict__ lossp)
{
    __shared__ float zt[BR * LDZ];
    __shared__ float et[BR * LDZ];
    __shared__ float lred[4];

    const int tid = threadIdx.x;
    const int rowbase = blockIdx.x * BR;

    // stage z tile (BR x DIM), coalesced float4
    {
        const float4* zg = reinterpret_cast<const float4*>(z + (size_t)rowbase * DIM);
#pragma unroll
        for (int p = 0; p < 8; p++) {
            int q = tid + p * 256;       // 0..2047 float4s
            int r = q >> 4;              // 16 float4 per row
            int c = q & 15;
            float4 v = zg[q];
            *reinterpret_cast<float4*>(&zt[r * LDZ + c * 4]) = v;
        }
    }

    const int tr = tid & 15;   // row group: rows tr + 16*i
    const int tc = tid >> 4;   // code group: codes cb + tc + 16*j

    float bestv[8];
    int   besti[8];
#pragma unroll
    for (int i = 0; i < 8; i++) { bestv[i] = 3.4e38f; besti[i] = 0; }

    for (int cb = 0; cb < NCODES; cb += BC) {
        __syncthreads();
        // stage e tile (BC x DIM)
        {
            const float4* eg = reinterpret_cast<const float4*>(emb + (size_t)cb * DIM);
#pragma unroll
            for (int p = 0; p < 8; p++) {
                int q = tid + p * 256;
                int r = q >> 4;
                int c = q & 15;
                float4 v = eg[q];
                *reinterpret_cast<float4*>(&et[r * LDZ + c * 4]) = v;
            }
        }
        __syncthreads();

        float acc[8][8];
#pragma unroll
        for (int i = 0; i < 8; i++)
#pragma unroll
            for (int j = 0; j < 8; j++) acc[i][j] = 0.f;

#pragma unroll 2
        for (int d = 0; d < DIM; d += 4) {
            float4 zv[8], ev[8];
#pragma unroll
            for (int i = 0; i < 8; i++)
                zv[i] = *reinterpret_cast<const float4*>(&zt[(tr + 16 * i) * LDZ + d]);
#pragma unroll
            for (int j = 0; j < 8; j++)
                ev[j] = *reinterpret_cast<const float4*>(&et[(tc + 16 * j) * LDZ + d]);
#pragma unroll
            for (int i = 0; i < 8; i++)
#pragma unroll
                for (int j = 0; j < 8; j++) {
                    acc[i][j] = fmaf(zv[i].x, ev[j].x, acc[i][j]);
                    acc[i][j] = fmaf(zv[i].y, ev[j].y, acc[i][j]);
                    acc[i][j] = fmaf(zv[i].z, ev[j].z, acc[i][j]);
                    acc[i][j] = fmaf(zv[i].w, ev[j].w, acc[i][j]);
                }
        }

        // score = ||e||^2 - 2*dot ; strict < keeps first occurrence (codes ascend with j)
#pragma unroll
        for (int j = 0; j < 8; j++) {
            int c = cb + tc + 16 * j;
            float eb = ebias[c];
#pragma unroll
            for (int i = 0; i < 8; i++) {
                float s = fmaf(-2.f, acc[i][j], eb);
                if (s < bestv[i]) { bestv[i] = s; besti[i] = c; }
            }
        }
    }

    // cross-thread (tc-group) argmin reduction; overlay on et
    __syncthreads();
    float* bv   = et;                                       // [BR][17]
    int*   bi   = reinterpret_cast<int*>(et + BR * 17);     // [BR][17]
    int*   sidx = reinterpret_cast<int*>(et + 2 * BR * 17); // [BR]
#pragma unroll
    for (int i = 0; i < 8; i++) {
        int r = tr + 16 * i;
        bv[r * 17 + tc] = bestv[i];
        bi[r * 17 + tc] = besti[i];
    }
    __syncthreads();
    if (tid < BR) {
        int r = tid;
        float v = bv[r * 17];
        int   ix = bi[r * 17];
#pragma unroll
        for (int t = 1; t < 16; t++) {
            float v2 = bv[r * 17 + t];
            int   i2 = bi[r * 17 + t];
            if (v2 < v || (v2 == v && i2 < ix)) { v = v2; ix = i2; }
        }
        sidx[r] = ix;
        out[OUT_IDX + rowbase + r] = (float)ix;
        atomicAdd(&counts[ix], 1.0f);
    }
    __syncthreads();

    // epilogue: gather e[idx], z_q_st, loss, dw scatter (z still in LDS)
    float lsum = 0.f;
    const int d  = tid & 63;
    const int rq = tid >> 6;
#pragma unroll
    for (int p = 0; p < 32; p++) {
        int r = p * 4 + rq;
        int ix = sidx[r];                      // wave-uniform broadcast
        float ev = emb[(size_t)ix * DIM + d];
        float zv = zt[r * LDZ + d];
        float zq = zv + (ev - zv);             // exact reference op order
        out[OUT_ZQ + (size_t)(rowbase + r) * DIM + d] = zq;
        float df = ev - zv;
        lsum = fmaf(df, df, lsum);
        atomicAdd(&dw[(size_t)ix * DIM + d], zv);
    }
#pragma unroll
    for (int o = 32; o > 0; o >>= 1) lsum += __shfl_down(lsum, o, 64);
    if ((tid & 63) == 0) lred[tid >> 6] = lsum;
    __syncthreads();
    if (tid == 0) lossp[blockIdx.x] = (lred[0] + lred[1]) + (lred[2] + lred[3]);
}

// new_cluster_size + its partial sums
__global__ void vq_ncs_kernel(const float* __restrict__ ema_cs, const float* __restrict__ counts,
                              float* __restrict__ out, float* __restrict__ ncsp) {
    __shared__ float r4[4];
    int k = blockIdx.x * 256 + threadIdx.x;
    float v = ema_cs[k] * 0.99f + counts[k] * 0.01f;
    out[OUT_NCS + k] = v;
    float s = v;
#pragma unroll
    for (int o = 32; o > 0; o >>= 1) s += __shfl_down(s, o, 64);
    if ((threadIdx.x & 63) == 0) r4[threadIdx.x >> 6] = s;
    __syncthreads();
    if (threadIdx.x == 0) ncsp[blockIdx.x] = (r4[0] + r4[1]) + (r4[2] + r4[3]);
}

// n = sum(ncs); vq_loss
__global__ void vq_finalize_kernel(const float* __restrict__ ncsp, const float* __restrict__ lossp,
                                   float* __restrict__ nout, float* __restrict__ out) {
    __shared__ float r4[4];
    int t = threadIdx.x;
    float ls = lossp[t] + lossp[t + 256];
#pragma unroll
    for (int o = 32; o > 0; o >>= 1) ls += __shfl_down(ls, o, 64);
    if ((t & 63) == 0) r4[t >> 6] = ls;
    __syncthreads();
    if (t == 0) {
        float total = (r4[0] + r4[1]) + (r4[2] + r4[3]);
        out[OUT_LOSS] = 0.25f * (total * (1.0f / 4194304.0f));
    }
    if (t < 64) {
        float nv = (t < 32) ? ncsp[t] : 0.f;
#pragma unroll
        for (int o = 32; o > 0; o >>= 1) nv += __shfl_down(nv, o, 64);
        if (t == 0) nout[0] = nv;
    }
}

// new_ema_embedding + new_embedding
__global__ void vq_embupd_kernel(const float* __restrict__ ema_emb, const float* __restrict__ dw,
                                 const float* __restrict__ ncs_out, const float* __restrict__ nptr,
                                 float* __restrict__ out) {
    int i = blockIdx.x * 256 + threadIdx.x;   // 0..524287
    int k = i >> 6;
    float nev = ema_emb[i] * 0.99f + dw[i] * 0.01f;
    out[OUT_NEMA + i] = nev;
    float n = nptr[0];
    float ncs = ncs_out[k];
    float cs = (ncs + 1e-5f) / (n + 8192.0f * 1e-5f) * n;
    out[OUT_NEMB + i] = nev / cs;
}

extern "C" void kernel_launch(void* const* d_in, const int* in_sizes, int n_in,
                              void* d_out, int out_size, void* d_ws, size_t ws_size,
                              hipStream_t stream) {
    (void)in_sizes; (void)n_in; (void)out_size; (void)ws_size;
    const float* z       = (const float*)d_in[0];
    const float* emb     = (const float*)d_in[1];
    const float* ema_cs  = (const float*)d_in[2];
    const float* ema_emb = (const float*)d_in[3];
    float* out = (float*)d_out;
    float* ws  = (float*)d_ws;

    hipMemsetAsync(ws + WS_COUNTS, 0, (size_t)(WS_END - WS_COUNTS) * sizeof(float), stream);
    vq_ebias_kernel<<<NCODES / 256, 256, 0, stream>>>(emb, ws + WS_EBIAS);
    vq_main_kernel<<<NROWS / BR, 256, 0, stream>>>(z, emb, ws + WS_EBIAS, out,
                                                   ws + WS_COUNTS, ws + WS_DW, ws + WS_LOSSP);
    vq_ncs_kernel<<<NCODES / 256, 256, 0, stream>>>(ema_cs, ws + WS_COUNTS, out, ws + WS_NCSP);
    vq_finalize_kernel<<<1, 256, 0, stream>>>(ws + WS_NCSP, ws + WS_LOSSP, ws + WS_N, out);
    vq_embupd_kernel<<<(NCODES * DIM) / 256, 256, 0, stream>>>(ema_emb, ws + WS_DW,
                                                               out + OUT_NCS, ws + WS_N, out);
}

// Round 7
// 696.541 us; speedup vs baseline: 1.3439x; 1.3439x over previous
//
#include <hip/hip_runtime.h>
#include <hip/hip_bf16.h>

#define NCODES 8192
#define DIM    64
#define NROWS  65536   // 16*4096

typedef __attribute__((ext_vector_type(8))) short short8v;
typedef __attribute__((ext_vector_type(4))) float f32x4;

// ---- workspace layout (float offsets). Total 541729 f32 ~= 2.17 MB
// (matches the round-2 baseline footprint that is PROVEN to fit ws_size;
//  the 19.5 MB layout of rounds 5/6 was never validated and is the prime
//  suspect for the margin-independent index corruption).
#define WS_EBIAS   0         // 8192 f32
#define WS_COUNTS  8192      // 8192 f32
#define WS_LOSSP   16384     // 1024 f32
#define WS_DW      17408     // 524288 f32  (bf16 eh aliases first 1 MB until phaseA done)
#define WS_NCSP    541696    // 32 f32
#define WS_N       541728    // 1 f32
#define WS_END     541729

// eh (bf16 emb, 524288 ushort = 1 MB) lives in the dw region until phase A
// completes; dw/counts/lossp are memset AFTER phase A, before phase B.
#define WS_EH      WS_DW

// cm (per-row per-64-code-chunk bf16 max-dot, 65536*128 ushort = 16.78 MB)
// lives in d_out's OUT_ZQ region: block b's tile = bytes [b*16384, (b+1)*16384)
// == exactly block b's z_q rows. Phase B stages tile->LDS, syncs, overwrites.

// ---- output layout (float offsets, tuple order) ----
#define OUT_ZQ     0
#define OUT_IDX    4194304
#define OUT_LOSS   4259840
#define OUT_NEMB   4259841
#define OUT_NCS    4784129
#define OUT_NEMA   4792321

// Screening margin: worst-case bf16(7-bit mantissa) dot error 2*2^-8*||z||max
// ~=0.087 per side + cm quant 0.031 -> 0.236 worst; 0.30 gives 27% headroom.
#define CUT_MARGIN 0.30f

__device__ __forceinline__ unsigned short f2b(float f) {
    unsigned u = __float_as_uint(f);
    return (unsigned short)((u + 0x7FFFu + ((u >> 16) & 1u)) >> 16);  // RNE
}
__device__ __forceinline__ float b2f(unsigned short h) {
    return __uint_as_float(((unsigned)h) << 16);
}

// ||e_k||^2 per code (f32, used for exact scores in phase B)
__global__ void vq_ebias_kernel(const float* __restrict__ emb, float* __restrict__ ebias) {
    int k = blockIdx.x * 256 + threadIdx.x;
    const float4* e4 = reinterpret_cast<const float4*>(emb + (size_t)k * DIM);
    float s = 0.f;
#pragma unroll
    for (int i = 0; i < 16; i++) {
        float4 v = e4[i];
        s = fmaf(v.x, v.x, s); s = fmaf(v.y, v.y, s);
        s = fmaf(v.z, v.z, s); s = fmaf(v.w, v.w, s);
    }
    ebias[k] = s;
}

// emb f32 -> bf16 (row-major [code][k])
__global__ void vq_eprep_kernel(const float* __restrict__ emb, short* __restrict__ eh) {
    int i = blockIdx.x * 256 + threadIdx.x;   // per 2 elems
    float2 v = *reinterpret_cast<const float2*>(emb + (size_t)i * 2);
    unsigned o = (unsigned)f2b(v.x) | ((unsigned)f2b(v.y) << 16);
    *reinterpret_cast<unsigned*>(eh + (size_t)i * 2) = o;
}

// Phase A: bf16 MFMA screening. Per (row, 64-code chunk) store chunk-max dot (bf16).
// cm layout: [rowblk(1024)][gchunk(128)][row_in_blk(64)] ushort, in OUT_ZQ region.
__global__ __launch_bounds__(256)
void vq_phaseA(const float* __restrict__ z, const short* __restrict__ eh,
               unsigned short* __restrict__ cm)
{
    const int tid = threadIdx.x;
    const int l = tid & 63, w = tid >> 6;
    const int rg = blockIdx.x >> 1;        // 256 row-groups of 256 rows
    const int half = blockIdx.x & 1;       // code half (4096 codes each)
    const int rowbase = rg * 256 + w * 64; // this wave's 64 rows
    const int kq0 = (l >> 4) * 8;          // lane's k-offset within a K=32 step

    // Loop-invariant B-fragments (z rows, bf16-converted in-register): [rt][kstep]
    short8v B[4][2];
#pragma unroll
    for (int rt = 0; rt < 4; rt++) {
        const float* zr = z + (size_t)(rowbase + rt * 16 + (l & 15)) * 64;
#pragma unroll
        for (int s = 0; s < 2; s++) {
            int k0 = s * 32 + kq0;
            float4 p0 = *reinterpret_cast<const float4*>(zr + k0);
            float4 p1 = *reinterpret_cast<const float4*>(zr + k0 + 4);
            short8v t;
            t[0] = (short)f2b(p0.x); t[1] = (short)f2b(p0.y);
            t[2] = (short)f2b(p0.z); t[3] = (short)f2b(p0.w);
            t[4] = (short)f2b(p1.x); t[5] = (short)f2b(p1.y);
            t[6] = (short)f2b(p1.z); t[7] = (short)f2b(p1.w);
            B[rt][s] = t;
        }
    }

    unsigned short* cmw = cm + (size_t)(rowbase >> 6) * 8192;

    for (int ch = 0; ch < 64; ch++) {
        const int gchunk = half * 64 + ch;
        const int cbase = gchunk * 64;
        // A-fragments: 64 codes of this chunk, straight from global (L2-hot)
        short8v A[4][2];
#pragma unroll
        for (int ct = 0; ct < 4; ct++) {
            const short* ep = eh + (size_t)(cbase + ct * 16 + (l & 15)) * 64;
            A[ct][0] = *reinterpret_cast<const short8v*>(ep + kq0);
            A[ct][1] = *reinterpret_cast<const short8v*>(ep + 32 + kq0);
        }
        float runmax[4] = {-3.4e38f, -3.4e38f, -3.4e38f, -3.4e38f};
#pragma unroll
        for (int ct = 0; ct < 4; ct++) {
#pragma unroll
            for (int rt = 0; rt < 4; rt++) {
                f32x4 acc = {0.f, 0.f, 0.f, 0.f};
                acc = __builtin_amdgcn_mfma_f32_16x16x32_bf16(A[ct][0], B[rt][0], acc, 0, 0, 0);
                acc = __builtin_amdgcn_mfma_f32_16x16x32_bf16(A[ct][1], B[rt][1], acc, 0, 0, 0);
                // D col = lane&15 = z row (rt tile); D row = (lane>>4)*4+reg = code
                float m = fmaxf(fmaxf(acc[0], acc[1]), fmaxf(acc[2], acc[3]));
                runmax[rt] = fmaxf(runmax[rt], m);
            }
        }
#pragma unroll
        for (int rt = 0; rt < 4; rt++) {
            float r1 = fmaxf(runmax[rt], __shfl_xor(runmax[rt], 16));
            float r2 = fmaxf(r1, __shfl_xor(r1, 32));
            if (l < 16) cmw[(size_t)gchunk * 64 + rt * 16 + l] = f2b(r2);
        }
    }
}

// Phase B: candidate scan + exact f32 recheck + fused epilogue. Wave-per-row group.
// Reads its cm tile from the OUT_ZQ region, then overwrites it with z_q.
__global__ __launch_bounds__(256)
void vq_phaseB(const float* __restrict__ z, const float* __restrict__ emb,
               const float* __restrict__ ebias, float* __restrict__ out,
               float* __restrict__ counts, float* __restrict__ dw,
               float* __restrict__ lossp)
{
    __shared__ float zlds[64 * 64];
    __shared__ unsigned short cmlds[128][68];
    __shared__ float lred[4];
    const int tid = threadIdx.x;
    const int l = tid & 63, w = tid >> 6;
    const int rowbase = blockIdx.x * 64;

    {   // stage z tile (64 rows x 64 dims f32)
        const float4* zg = reinterpret_cast<const float4*>(z + (size_t)rowbase * 64);
        for (int i = tid; i < 1024; i += 256)
            reinterpret_cast<float4*>(zlds)[i] = zg[i];
    }
    {   // stage this block's cm tile from OUT_ZQ region: [chunk][row]
        const unsigned short* g =
            reinterpret_cast<const unsigned short*>(out + OUT_ZQ) + (size_t)blockIdx.x * 8192;
#pragma unroll
        for (int p = 0; p < 4; p++) {
            int idx = tid + p * 256;                 // ushort8 index 0..1023
            uint4 v = *reinterpret_cast<const uint4*>(g + idx * 8);
            int chunk = idx >> 3, rs = (idx & 7) * 8;
            *reinterpret_cast<uint2*>(&cmlds[chunk][rs])     = make_uint2(v.x, v.y);
            *reinterpret_cast<uint2*>(&cmlds[chunk][rs + 4]) = make_uint2(v.z, v.w);
        }
    }
    __syncthreads();   // cm tile fully in LDS; safe to overwrite with z_q below

    float lacc = 0.f;
    for (int p = 0; p < 16; p++) {
        const int row = w * 16 + p;
        const int grow = rowbase + row;
        float f0 = b2f(cmlds[l][row]);
        float f1 = b2f(cmlds[l + 64][row]);
        float M = fmaxf(f0, f1);
#pragma unroll
        for (int o = 1; o < 64; o <<= 1) M = fmaxf(M, __shfl_xor(M, o));
        const float cut = M - CUT_MARGIN;
        unsigned long long m0 = __ballot(f0 >= cut);
        unsigned long long m1 = __ballot(f1 >= cut);

        float best = 3.4e38f; int bidx = 0;
        const float* zr = zlds + row * 64;
        while (m0 | m1) {   // ascending chunk order -> first-occurrence ties
            int c;
            if (m0) { c = __ffsll(m0) - 1; m0 &= m0 - 1; }
            else    { c = 64 + __ffsll(m1) - 1; m1 &= m1 - 1; }
            int code = c * 64 + l;
            const float4* ef = reinterpret_cast<const float4*>(emb + (size_t)code * 64);
            float dot = 0.f;
#pragma unroll 8
            for (int d = 0; d < 16; d++) {
                float4 e4 = ef[d];
                float4 z4 = *reinterpret_cast<const float4*>(zr + d * 4);
                dot = fmaf(e4.x, z4.x, dot); dot = fmaf(e4.y, z4.y, dot);
                dot = fmaf(e4.z, z4.z, dot); dot = fmaf(e4.w, z4.w, dot);
            }
            float s = fmaf(-2.f, dot, ebias[code]);
            if (s < best) { best = s; bidx = code; }   // strict <: earlier code wins ties
        }
#pragma unroll
        for (int o = 1; o < 64; o <<= 1) {
            float ov = __shfl_xor(best, o);
            int oi = __shfl_xor(bidx, o);
            if (ov < best || (ov == best && oi < bidx)) { best = ov; bidx = oi; }
        }
        // fused epilogue: lane = dim
        float ev = emb[(size_t)bidx * 64 + l];
        float zv = zr[l];
        out[OUT_ZQ + (size_t)grow * 64 + l] = zv + (ev - zv);
        float df = ev - zv;
        lacc = fmaf(df, df, lacc);
        atomicAdd(&dw[(size_t)bidx * 64 + l], zv);
        if (l == 0) {
            out[OUT_IDX + grow] = (float)bidx;
            atomicAdd(&counts[bidx], 1.0f);
        }
    }
#pragma unroll
    for (int o = 1; o < 64; o <<= 1) lacc += __shfl_xor(lacc, o);
    if (l == 0) lred[w] = lacc;
    __syncthreads();
    if (tid == 0) lossp[blockIdx.x] = (lred[0] + lred[1]) + (lred[2] + lred[3]);
}

// new_cluster_size + partial sums
__global__ void vq_ncs_kernel(const float* __restrict__ ema_cs, const float* __restrict__ counts,
                              float* __restrict__ out, float* __restrict__ ncsp) {
    __shared__ float r4[4];
    int k = blockIdx.x * 256 + threadIdx.x;
    float v = ema_cs[k] * 0.99f + counts[k] * 0.01f;
    out[OUT_NCS + k] = v;
    float s = v;
#pragma unroll
    for (int o = 32; o > 0; o >>= 1) s += __shfl_down(s, o, 64);
    if ((threadIdx.x & 63) == 0) r4[threadIdx.x >> 6] = s;
    __syncthreads();
    if (threadIdx.x == 0) ncsp[blockIdx.x] = (r4[0] + r4[1]) + (r4[2] + r4[3]);
}

// n = sum(ncs); vq_loss
__global__ void vq_finalize_kernel(const float* __restrict__ ncsp, const float* __restrict__ lossp,
                                   float* __restrict__ nout, float* __restrict__ out) {
    __shared__ float r4[4];
    int t = threadIdx.x;
    float ls = (lossp[t] + lossp[t + 256]) + (lossp[t + 512] + lossp[t + 768]);
#pragma unroll
    for (int o = 32; o > 0; o >>= 1) ls += __shfl_down(ls, o, 64);
    if ((t & 63) == 0) r4[t >> 6] = ls;
    __syncthreads();
    if (t == 0) {
        float total = (r4[0] + r4[1]) + (r4[2] + r4[3]);
        out[OUT_LOSS] = 0.25f * (total * (1.0f / 4194304.0f));
    }
    if (t < 64) {
        float nv = (t < 32) ? ncsp[t] : 0.f;
#pragma unroll
        for (int o = 32; o > 0; o >>= 1) nv += __shfl_down(nv, o, 64);
        if (t == 0) nout[0] = nv;
    }
}

// new_ema_embedding + new_embedding
__global__ void vq_embupd_kernel(const float* __restrict__ ema_emb, const float* __restrict__ dw,
                                 const float* __restrict__ ncs_out, const float* __restrict__ nptr,
                                 float* __restrict__ out) {
    int i = blockIdx.x * 256 + threadIdx.x;
    int k = i >> 6;
    float nev = ema_emb[i] * 0.99f + dw[i] * 0.01f;
    out[OUT_NEMA + i] = nev;
    float n = nptr[0];
    float ncs = ncs_out[k];
    float cs = (ncs + 1e-5f) / (n + 8192.0f * 1e-5f) * n;
    out[OUT_NEMB + i] = nev / cs;
}

extern "C" void kernel_launch(void* const* d_in, const int* in_sizes, int n_in,
                              void* d_out, int out_size, void* d_ws, size_t ws_size,
                              hipStream_t stream) {
    (void)in_sizes; (void)n_in; (void)out_size; (void)ws_size;
    const float* z       = (const float*)d_in[0];
    const float* emb     = (const float*)d_in[1];
    const float* ema_cs  = (const float*)d_in[2];
    const float* ema_emb = (const float*)d_in[3];
    float* out = (float*)d_out;
    float* ws  = (float*)d_ws;

    short* eh          = (short*)(ws + WS_EH);                     // aliases dw region
    unsigned short* cm = (unsigned short*)(out + OUT_ZQ);          // aliases z_q region

    vq_ebias_kernel<<<NCODES / 256, 256, 0, stream>>>(emb, ws + WS_EBIAS);
    vq_eprep_kernel<<<(NCODES * DIM / 2) / 256, 256, 0, stream>>>(emb, eh);
    vq_phaseA<<<512, 256, 0, stream>>>(z, eh, cm);
    // eh dead now; zero counts + lossp + dw (one contiguous range) before phase B
    hipMemsetAsync(ws + WS_COUNTS, 0,
                   (size_t)(WS_DW + NCODES * DIM - WS_COUNTS) * sizeof(float), stream);
    vq_phaseB<<<1024, 256, 0, stream>>>(z, emb, ws + WS_EBIAS,
                                        out, ws + WS_COUNTS, ws + WS_DW, ws + WS_LOSSP);
    vq_ncs_kernel<<<NCODES / 256, 256, 0, stream>>>(ema_cs, ws + WS_COUNTS, out, ws + WS_NCSP);
    vq_finalize_kernel<<<1, 256, 0, stream>>>(ws + WS_NCSP, ws + WS_LOSSP, ws + WS_N, out);
    vq_embupd_kernel<<<(NCODES * DIM) / 256, 256, 0, stream>>>(ema_emb, ws + WS_DW,
                                                               out + OUT_NCS, ws + WS_N, out);
}